// Round 10
// baseline (2905.023 us; speedup 1.0000x reference)
//
#include <hip/hip_runtime.h>

#define N_NODES 100000
#define N_EDGES 1600000
#define N_GRAPHS 512
#define DIM 128
#define NCLS 10
#define NBKT 782          // buckets of 128 dst nodes: 782*128 = 100096 >= N
#define BCAP 2560         // padded bucket region (mean 2048, sigma~45 -> 11 sigma slack)

typedef __attribute__((ext_vector_type(8))) short short8;
typedef __attribute__((ext_vector_type(4))) float f32x4;

static __device__ __forceinline__ unsigned short f2bf(float f) {
    unsigned u = __float_as_uint(f);
    unsigned r = (u + 0x7FFF + ((u >> 16) & 1)) >> 16;  // RNE
    return (unsigned short)r;
}
static __device__ __forceinline__ float bf2f(unsigned u) {
    return __uint_as_float(u << 16);
}

// ---------------- W fragment prep + bcnt zero (one launch) ----------------
// blocks 0..63: W1; 64..127: W2; 128..: zero bcnt.

__global__ void k_wprep(const float* __restrict__ W1, const float* __restrict__ W2,
                        unsigned short* __restrict__ wf1, unsigned short* __restrict__ wf2,
                        int* __restrict__ bcnt) {
    int b = blockIdx.x;
    if (b >= 128) {
        int i = (b - 128) * 256 + threadIdx.x;
        if (i < NBKT) bcnt[i] = 0;
        return;
    }
    const float* W = (b < 64) ? W1 : W2;
    unsigned short* wfrag = (b < 64) ? wf1 : wf2;
    int t = (b & 63) * 256 + threadIdx.x;   // 0..16383
    int j = t & 7, lane = (t >> 3) & 63, nt = (t >> 9) & 7, kit = t >> 12;
    int k = kit * 32 + (lane >> 4) * 8 + j;
    int n = nt * 16 + (lane & 15);
    float v = W[k * 128 + n];
    unsigned short h = f2bf(v);
    wfrag[t] = h;
    wfrag[16384 + t] = f2bf(v - bf2f(h));
}

// ---------------- edge prep phase A: padded bucketing (R7 measured-fast shape) ----------------

__global__ __launch_bounds__(256) void k_bucket(
    const int* __restrict__ src, const int* __restrict__ dst,
    int* __restrict__ bcnt, unsigned* __restrict__ bpack, int E) {
    __shared__ int cnt[NBKT];
    __shared__ int base[NBKT];
    int tid = threadIdx.x;
    for (int i = tid; i < NBKT; i += 256) cnt[i] = 0;
    __syncthreads();
    int e0 = blockIdx.x * 4096 + tid;
    unsigned pk[16]; short bk[16];
#pragma unroll
    for (int j = 0; j < 16; j++) {
        int e = e0 + j * 256;
        if (e < E) {
            int s = src[e], d = dst[e];
            bk[j] = (short)(d >> 7);
            pk[j] = ((unsigned)(d & 127) << 17) | (unsigned)s;
            atomicAdd(&cnt[bk[j]], 1);
        } else bk[j] = -1;
    }
    __syncthreads();
    for (int i = tid; i < NBKT; i += 256) {
        int c = cnt[i];
        base[i] = c ? atomicAdd(&bcnt[i], c) : 0;
        cnt[i] = 0;
    }
    __syncthreads();
#pragma unroll
    for (int j = 0; j < 16; j++) {
        if (bk[j] >= 0) {
            int p = base[bk[j]] + atomicAdd(&cnt[bk[j]], 1);
            if (p < BCAP) bpack[(size_t)bk[j] * BCAP + p] = pk[j];
        }
    }
}

// ---------------- degree -> dinv (replaces full CSR bsort: no scan, no scatter) ----------------

__global__ __launch_bounds__(256) void k_deg(
    const unsigned* __restrict__ bpack, const int* __restrict__ bcnt,
    float* __restrict__ dinv, int N) {
    __shared__ int cnt[128];
    int b = blockIdx.x, tid = threadIdx.x;
    if (tid < 128) cnt[tid] = 0;
    __syncthreads();
    int m = min(bcnt[b], BCAP);
    const unsigned* bp = bpack + (size_t)b * BCAP;
    for (int j = tid; j < m; j += 256) atomicAdd(&cnt[bp[j] >> 17], 1);
    __syncthreads();
    int node = (b << 7) + tid;
    if (tid < 128 && node < N) dinv[node] = rsqrtf((float)(cnt[tid] + 1));  // +1 self loop
}

// ---------------- MFMA GEMM (fp32 A): ybf = bf16(dinv * (A @ W)) ----------------

__global__ __launch_bounds__(256) void k_gemm_f32(
    const float* __restrict__ A, const unsigned short* __restrict__ wfrag,
    const float* __restrict__ dinv, unsigned short* __restrict__ ybf, int M) {
    __shared__ unsigned short ldsw[4 * 32 * 136];   // K-loop = W-hi(16384); epilogue = scr
    int tid = threadIdx.x, wave = tid >> 6, lane = tid & 63;
    int m = lane & 15, quad = lane >> 4;
    int rowBase = blockIdx.x * 128 + wave * 32;
    int r0 = rowBase + m, r1 = rowBase + 16 + m;
    for (int i = tid; i < 2048; i += 256)
        ((short8*)ldsw)[i] = ((const short8*)wfrag)[i];   // stage W-hi
    __syncthreads();
    f32x4 acc0[8], acc1[8];
#pragma unroll
    for (int i = 0; i < 8; i++) { acc0[i] = (f32x4){0,0,0,0}; acc1[i] = (f32x4){0,0,0,0}; }
    const unsigned short* wlo = wfrag + 16384;

#pragma unroll
    for (int kit = 0; kit < 4; kit++) {
        float a0[8], a1[8];
        if (r0 < M) {
            const float4* ap = (const float4*)(A + (size_t)r0 * 128 + kit * 32 + quad * 8);
            float4 f0 = ap[0], f1 = ap[1];
            a0[0]=f0.x; a0[1]=f0.y; a0[2]=f0.z; a0[3]=f0.w; a0[4]=f1.x; a0[5]=f1.y; a0[6]=f1.z; a0[7]=f1.w;
        } else { for (int j = 0; j < 8; j++) a0[j] = 0.f; }
        if (r1 < M) {
            const float4* ap = (const float4*)(A + (size_t)r1 * 128 + kit * 32 + quad * 8);
            float4 f0 = ap[0], f1 = ap[1];
            a1[0]=f0.x; a1[1]=f0.y; a1[2]=f0.z; a1[3]=f0.w; a1[4]=f1.x; a1[5]=f1.y; a1[6]=f1.z; a1[7]=f1.w;
        } else { for (int j = 0; j < 8; j++) a1[j] = 0.f; }
        short8 ahi0, alo0, ahi1, alo1;
#pragma unroll
        for (int j = 0; j < 8; j++) {
            unsigned short h0 = f2bf(a0[j]);
            ahi0[j] = (short)h0; alo0[j] = (short)f2bf(a0[j] - bf2f(h0));
            unsigned short h1 = f2bf(a1[j]);
            ahi1[j] = (short)h1; alo1[j] = (short)f2bf(a1[j] - bf2f(h1));
        }
        int fb = kit * 4096 + lane * 8;
#pragma unroll
        for (int nt = 0; nt < 8; nt++) {
            int idx = fb + nt * 512;
            short8 bhi = *(const short8*)(ldsw + idx);
            short8 blo = *(const short8*)(wlo + idx);
            acc0[nt] = __builtin_amdgcn_mfma_f32_16x16x32_bf16(ahi0, bhi, acc0[nt], 0, 0, 0);
            acc0[nt] = __builtin_amdgcn_mfma_f32_16x16x32_bf16(alo0, bhi, acc0[nt], 0, 0, 0);
            acc0[nt] = __builtin_amdgcn_mfma_f32_16x16x32_bf16(ahi0, blo, acc0[nt], 0, 0, 0);
            acc1[nt] = __builtin_amdgcn_mfma_f32_16x16x32_bf16(ahi1, bhi, acc1[nt], 0, 0, 0);
            acc1[nt] = __builtin_amdgcn_mfma_f32_16x16x32_bf16(alo1, bhi, acc1[nt], 0, 0, 0);
            acc1[nt] = __builtin_amdgcn_mfma_f32_16x16x32_bf16(ahi1, blo, acc1[nt], 0, 0, 0);
        }
    }
    __syncthreads();
    float dv0 = (r0 < M) ? dinv[r0] : 0.f;
    float dv1 = (r1 < M) ? dinv[r1] : 0.f;
    unsigned short* wsm = ldsw + wave * 32 * 136;
#pragma unroll
    for (int rg = 0; rg < 4; rg++) {
        float s0 = __shfl(dv0, quad * 4 + rg);
        float s1 = __shfl(dv1, quad * 4 + rg);
#pragma unroll
        for (int nt = 0; nt < 8; nt++) {
            wsm[(quad * 4 + rg) * 136 + nt * 16 + m] = f2bf(acc0[nt][rg] * s0);
            wsm[(16 + quad * 4 + rg) * 136 + nt * 16 + m] = f2bf(acc1[nt][rg] * s1);
        }
    }
    __syncthreads();
#pragma unroll
    for (int i = 0; i < 8; i++) {
        int rl = i * 4 + quad;
        int grow = rowBase + rl;
        if (grow < M) {
            short8 v = *(const short8*)(wsm + rl * 136 + m * 8);
            *(short8*)(ybf + (size_t)grow * 128 + m * 8) = v;
        }
    }
}

// ---------------- MFMA GEMM (bf16 A, exact): ybf = bf16(dinv * (A @ W)) ----------------

__global__ __launch_bounds__(256) void k_gemm_bf(
    const unsigned short* __restrict__ A, const unsigned short* __restrict__ wfrag,
    const float* __restrict__ dinv, unsigned short* __restrict__ ybf, int M) {
    __shared__ unsigned short ldsw[4 * 32 * 136];
    int tid = threadIdx.x, wave = tid >> 6, lane = tid & 63;
    int m = lane & 15, quad = lane >> 4;
    int rowBase = blockIdx.x * 128 + wave * 32;
    int r0 = rowBase + m, r1 = rowBase + 16 + m;
    for (int i = tid; i < 2048; i += 256)
        ((short8*)ldsw)[i] = ((const short8*)wfrag)[i];   // stage W-hi
    __syncthreads();
    f32x4 acc0[8], acc1[8];
#pragma unroll
    for (int i = 0; i < 8; i++) { acc0[i] = (f32x4){0,0,0,0}; acc1[i] = (f32x4){0,0,0,0}; }
    const unsigned short* wlo = wfrag + 16384;

#pragma unroll
    for (int kit = 0; kit < 4; kit++) {
        short8 ah0, ah1;
        if (r0 < M) ah0 = *(const short8*)(A + (size_t)r0 * 128 + kit * 32 + quad * 8);
        else { for (int j = 0; j < 8; j++) ah0[j] = 0; }
        if (r1 < M) ah1 = *(const short8*)(A + (size_t)r1 * 128 + kit * 32 + quad * 8);
        else { for (int j = 0; j < 8; j++) ah1[j] = 0; }
        int fb = kit * 4096 + lane * 8;
#pragma unroll
        for (int nt = 0; nt < 8; nt++) {
            int idx = fb + nt * 512;
            short8 bhi = *(const short8*)(ldsw + idx);
            short8 blo = *(const short8*)(wlo + idx);
            acc0[nt] = __builtin_amdgcn_mfma_f32_16x16x32_bf16(ah0, bhi, acc0[nt], 0, 0, 0);
            acc0[nt] = __builtin_amdgcn_mfma_f32_16x16x32_bf16(ah0, blo, acc0[nt], 0, 0, 0);
            acc1[nt] = __builtin_amdgcn_mfma_f32_16x16x32_bf16(ah1, bhi, acc1[nt], 0, 0, 0);
            acc1[nt] = __builtin_amdgcn_mfma_f32_16x16x32_bf16(ah1, blo, acc1[nt], 0, 0, 0);
        }
    }
    __syncthreads();
    float dv0 = (r0 < M) ? dinv[r0] : 0.f;
    float dv1 = (r1 < M) ? dinv[r1] : 0.f;
    unsigned short* wsm = ldsw + wave * 32 * 136;
#pragma unroll
    for (int rg = 0; rg < 4; rg++) {
        float s0 = __shfl(dv0, quad * 4 + rg);
        float s1 = __shfl(dv1, quad * 4 + rg);
#pragma unroll
        for (int nt = 0; nt < 8; nt++) {
            wsm[(quad * 4 + rg) * 136 + nt * 16 + m] = f2bf(acc0[nt][rg] * s0);
            wsm[(16 + quad * 4 + rg) * 136 + nt * 16 + m] = f2bf(acc1[nt][rg] * s1);
        }
    }
    __syncthreads();
#pragma unroll
    for (int i = 0; i < 8; i++) {
        int rl = i * 4 + quad;
        int grow = rowBase + rl;
        if (grow < M) {
            short8 v = *(const short8*)(wsm + rl * 136 + m * 8);
            *(short8*)(ybf + (size_t)grow * 128 + m * 8) = v;
        }
    }
}

// ---------------- bucket-direct aggregation: LDS fp32 accumulator, no CSR ----------------
// Block = one 128-node bucket, 512 thr (8 waves), 64KB LDS acc[128][128].
// Waves stream the bucket's packed edges (coalesced chunk + shfl broadcast);
// each edge: 64-lane 256B row gather + ds_add_f32 into acc[dstlocal][*].
// Epilogue adds self-loop row, applies dinv/bias/relu, writes bf16.
// Gather traffic unchanged vs CSR agg (fabric floor); esrc/rp reads eliminated.

__global__ __launch_bounds__(512) void k_agg(
    const unsigned short* __restrict__ y, const float* __restrict__ dinv,
    const unsigned* __restrict__ bpack, const int* __restrict__ bcnt,
    const float* __restrict__ bias, unsigned* __restrict__ out, int relu, int N) {
    __shared__ float acc[128 * 128];   // 64 KB
    int b = blockIdx.x, tid = threadIdx.x;
    int wave = tid >> 6, lane = tid & 63;
    float4* a4 = (float4*)acc;
    for (int i = tid; i < 4096; i += 512) a4[i] = make_float4(0.f, 0.f, 0.f, 0.f);
    __syncthreads();
    int m = min(bcnt[b], BCAP);
    const unsigned* bp = bpack + (size_t)b * BCAP;
    const unsigned* y2 = (const unsigned*)y;   // 2 bf16 per u32, row stride 64
    int lo = (int)(((long long)m * wave) >> 3);
    int hi = (int)(((long long)m * (wave + 1)) >> 3);
    int j = lo;
    while (j < hi) {
        unsigned ev = (j + lane < hi) ? bp[j + lane] : 0u;
        int cnt = hi - j; if (cnt > 64) cnt = 64;
        int i = 0;
        for (; i + 4 <= cnt; i += 4) {
            unsigned e0 = __shfl(ev, i + 0);
            unsigned e1 = __shfl(ev, i + 1);
            unsigned e2 = __shfl(ev, i + 2);
            unsigned e3 = __shfl(ev, i + 3);
            unsigned v0 = y2[(size_t)(e0 & 0x1FFFF) * 64 + lane];
            unsigned v1 = y2[(size_t)(e1 & 0x1FFFF) * 64 + lane];
            unsigned v2 = y2[(size_t)(e2 & 0x1FFFF) * 64 + lane];
            unsigned v3 = y2[(size_t)(e3 & 0x1FFFF) * 64 + lane];
            float* p0 = acc + ((e0 >> 17) << 7) + lane * 2;
            atomicAdd(p0, bf2f(v0 & 0xFFFF));  atomicAdd(p0 + 1, bf2f(v0 >> 16));
            float* p1 = acc + ((e1 >> 17) << 7) + lane * 2;
            atomicAdd(p1, bf2f(v1 & 0xFFFF));  atomicAdd(p1 + 1, bf2f(v1 >> 16));
            float* p2 = acc + ((e2 >> 17) << 7) + lane * 2;
            atomicAdd(p2, bf2f(v2 & 0xFFFF));  atomicAdd(p2 + 1, bf2f(v2 >> 16));
            float* p3 = acc + ((e3 >> 17) << 7) + lane * 2;
            atomicAdd(p3, bf2f(v3 & 0xFFFF));  atomicAdd(p3 + 1, bf2f(v3 >> 16));
        }
        for (; i < cnt; i++) {
            unsigned e = __shfl(ev, i);
            unsigned v = y2[(size_t)(e & 0x1FFFF) * 64 + lane];
            float* p = acc + ((e >> 17) << 7) + lane * 2;
            atomicAdd(p, bf2f(v & 0xFFFF));  atomicAdd(p + 1, bf2f(v >> 16));
        }
        j += cnt;
    }
    __syncthreads();
    int n0 = b << 7;
#pragma unroll
    for (int k = 0; k < 16; k++) {
        int linear = k * 512 + tid;        // 0..8191: node-major, coalesced stores
        int nl = linear >> 6;              // 0..127
        int fp = linear & 63;              // feature pair
        int node = n0 + nl;
        if (node < N) {
            unsigned sv = y2[(size_t)node * 64 + fp];   // self loop
            float o0 = acc[nl * 128 + fp * 2]     + bf2f(sv & 0xFFFF);
            float o1 = acc[nl * 128 + fp * 2 + 1] + bf2f(sv >> 16);
            float dv = dinv[node];
            float2 bv = ((const float2*)bias)[fp];
            o0 = dv * o0 + bv.x;
            o1 = dv * o1 + bv.y;
            if (relu) { o0 = fmaxf(o0, 0.f); o1 = fmaxf(o1, 0.f); }
            out[(size_t)node * 64 + fp] = (unsigned)f2bf(o0) | ((unsigned)f2bf(o1) << 16);
        }
    }
}

// ---------------- fused mean-pool + classifier head ----------------

__global__ __launch_bounds__(256) void k_poolhead(
    const unsigned* __restrict__ h2, const int* __restrict__ batch,
    const float* __restrict__ Wc, const float* __restrict__ bc,
    float* __restrict__ out, int n) {
    __shared__ float2 red[4][64];
    __shared__ float grow[DIM];
    int gid = blockIdx.x;
    int tid = threadIdx.x, wave = tid >> 6, lane = tid & 63;
    int lo = 0, hi = n;
    while (lo < hi) { int mid = (lo + hi) >> 1; if (batch[mid] < gid) lo = mid + 1; else hi = mid; }
    int start = lo;
    hi = n;
    while (lo < hi) { int mid = (lo + hi) >> 1; if (batch[mid] < gid + 1) lo = mid + 1; else hi = mid; }
    int end = lo;
    float a0 = 0.f, a1 = 0.f;
    for (int r = start + wave; r < end; r += 4) {
        unsigned v = h2[(size_t)r * 64 + lane];
        a0 += bf2f(v & 0xFFFF); a1 += bf2f(v >> 16);
    }
    red[wave][lane] = make_float2(a0, a1);
    __syncthreads();
    if (tid < 64) {
        float2 s = red[0][tid];
        s.x += red[1][tid].x; s.y += red[1][tid].y;
        s.x += red[2][tid].x; s.y += red[2][tid].y;
        s.x += red[3][tid].x; s.y += red[3][tid].y;
        int cnt = end - start;
        float inv = 1.f / (float)(cnt > 0 ? cnt : 1);
        grow[tid * 2] = s.x * inv;
        grow[tid * 2 + 1] = s.y * inv;
    }
    __syncthreads();
    if (tid < NCLS) {
        float acc = bc[tid];
#pragma unroll 16
        for (int k = 0; k < DIM; k++) acc += grow[k] * Wc[k * NCLS + tid];
        out[gid * NCLS + tid] = acc;
    }
}

extern "C" void kernel_launch(void* const* d_in, const int* in_sizes, int n_in,
                              void* d_out, int out_size, void* d_ws, size_t ws_size,
                              hipStream_t stream) {
    const float* x    = (const float*)d_in[0];
    const int*   ei   = (const int*)d_in[1];
    const int*   batch= (const int*)d_in[2];
    const float* W1   = (const float*)d_in[3];
    const float* b1   = (const float*)d_in[4];
    const float* W2   = (const float*)d_in[5];
    const float* b2   = (const float*)d_in[6];
    const float* Wc   = (const float*)d_in[7];
    const float* bc   = (const float*)d_in[8];
    float* out = (float*)d_out;
    const int N = N_NODES, E = N_EDGES;
    const int* src = ei;
    const int* dst = ei + E;

    char* ws = (char*)d_ws;
    size_t off = 0;
    auto carve = [&](size_t bytes) -> void* {
        void* p = ws + off;
        off = (off + bytes + 255) & ~(size_t)255;
        return p;
    };
    float*    dinv  = (float*)   carve((size_t)N * 4);
    int*      bcnt  = (int*)     carve(NBKT * 4);
    unsigned* bpack = (unsigned*)carve((size_t)NBKT * BCAP * 4);
    unsigned short* wf1 = (unsigned short*)carve(2 * 16384 * 2);
    unsigned short* wf2 = (unsigned short*)carve(2 * 16384 * 2);
    unsigned short* bufY = (unsigned short*)carve((size_t)N * DIM * 2);
    unsigned short* bufH = (unsigned short*)carve((size_t)N * DIM * 2);
    (void)ws_size; (void)n_in; (void)in_sizes; (void)out_size;

    hipLaunchKernelGGL(k_wprep,  dim3(128 + (NBKT + 255) / 256), dim3(256), 0, stream, W1, W2, wf1, wf2, bcnt);
    hipLaunchKernelGGL(k_bucket, dim3((E + 4095) / 4096), dim3(256), 0, stream, src, dst, bcnt, bpack, E);
    hipLaunchKernelGGL(k_deg,    dim3(NBKT), dim3(256), 0, stream, bpack, bcnt, dinv, N);

    int gemmGrid = (N + 127) / 128;  // 782
    // conv1: Y1 = bf16(dinv*(x@W1)); H1 = bf16(relu(dinv*agg(Y1)+b1))
    hipLaunchKernelGGL(k_gemm_f32, dim3(gemmGrid), dim3(256), 0, stream, x, wf1, dinv, bufY, N);
    hipLaunchKernelGGL(k_agg, dim3(NBKT), dim3(512), 0, stream, bufY, dinv, bpack, bcnt, b1, (unsigned*)bufH, 1, N);
    // conv2
    hipLaunchKernelGGL(k_gemm_bf, dim3(gemmGrid), dim3(256), 0, stream, bufH, wf2, dinv, bufY, N);
    hipLaunchKernelGGL(k_agg, dim3(NBKT), dim3(512), 0, stream, bufY, dinv, bpack, bcnt, b2, (unsigned*)bufH, 0, N);
    // fused pool + head
    hipLaunchKernelGGL(k_poolhead, dim3(N_GRAPHS), dim3(256), 0, stream, (const unsigned*)bufH, batch, Wc, bc, out, N);
}

// Round 11
// 342.886 us; speedup vs baseline: 8.4723x; 8.4723x over previous
//
#include <hip/hip_runtime.h>

#define N_NODES 100000
#define N_EDGES 1600000
#define N_GRAPHS 512
#define DIM 128
#define NCLS 10
#define NBKT 782          // buckets of 128 dst nodes: 782*128 = 100096 >= N
#define BCAP 2560         // padded bucket region (mean 2048, sigma~45 -> 11 sigma slack)

typedef __attribute__((ext_vector_type(8))) short short8;
typedef __attribute__((ext_vector_type(4))) float f32x4;

static __device__ __forceinline__ unsigned short f2bf(float f) {
    unsigned u = __float_as_uint(f);
    unsigned r = (u + 0x7FFF + ((u >> 16) & 1)) >> 16;  // RNE
    return (unsigned short)r;
}
static __device__ __forceinline__ float bf2f(unsigned u) {
    return __uint_as_float(u << 16);
}

// ---------------- W fragment prep + bcnt zero (one launch) ----------------
// blocks 0..63: W1; 64..127: W2; 128..131: zero bcnt.
// wfrag[hi: t<16384][lo: +16384], t = ((kit*8+nt)*64+lane)*8+j
// B element: k = kit*32 + (lane>>4)*8 + j, n = nt*16 + (lane&15)

__global__ void k_wprep(const float* __restrict__ W1, const float* __restrict__ W2,
                        unsigned short* __restrict__ wf1, unsigned short* __restrict__ wf2,
                        int* __restrict__ bcnt) {
    int b = blockIdx.x;
    if (b >= 128) {
        int i = (b - 128) * 256 + threadIdx.x;
        if (i < NBKT) bcnt[i] = 0;
        return;
    }
    const float* W = (b < 64) ? W1 : W2;
    unsigned short* wfrag = (b < 64) ? wf1 : wf2;
    int t = (b & 63) * 256 + threadIdx.x;   // 0..16383
    int j = t & 7, lane = (t >> 3) & 63, nt = (t >> 9) & 7, kit = t >> 12;
    int k = kit * 32 + (lane >> 4) * 8 + j;
    int n = nt * 16 + (lane & 15);
    float v = W[k * 128 + n];
    unsigned short h = f2bf(v);
    wfrag[t] = h;
    wfrag[16384 + t] = f2bf(v - bf2f(h));
}

// ---------------- edge prep phase A: padded bucketing ----------------

__global__ __launch_bounds__(256) void k_bucket(
    const int* __restrict__ src, const int* __restrict__ dst,
    int* __restrict__ bcnt, unsigned* __restrict__ bpack, int E) {
    __shared__ int cnt[NBKT];
    __shared__ int base[NBKT];
    int tid = threadIdx.x;
    for (int i = tid; i < NBKT; i += 256) cnt[i] = 0;
    __syncthreads();
    int e0 = blockIdx.x * 4096 + tid;
    unsigned pk[16]; short bk[16];
#pragma unroll
    for (int j = 0; j < 16; j++) {
        int e = e0 + j * 256;
        if (e < E) {
            int s = src[e], d = dst[e];
            bk[j] = (short)(d >> 7);
            pk[j] = ((unsigned)(d & 127) << 17) | (unsigned)s;
            atomicAdd(&cnt[bk[j]], 1);
        } else bk[j] = -1;
    }
    __syncthreads();
    for (int i = tid; i < NBKT; i += 256) {
        int c = cnt[i];
        base[i] = c ? atomicAdd(&bcnt[i], c) : 0;
        cnt[i] = 0;
    }
    __syncthreads();
#pragma unroll
    for (int j = 0; j < 16; j++) {
        if (bk[j] >= 0) {
            int p = base[bk[j]] + atomicAdd(&cnt[bk[j]], 1);
            if (p < BCAP) bpack[(size_t)bk[j] * BCAP + p] = pk[j];
        }
    }
}

// ---------------- edge prep phase B: per-bucket CSR build (self-scanned base) ----------------

__global__ __launch_bounds__(256) void k_bsort(
    const unsigned* __restrict__ bpack, const int* __restrict__ bcnt,
    int* __restrict__ rp, float* __restrict__ dinv,
    int* __restrict__ esrc, int N) {
    __shared__ int lds[256];
    __shared__ int gbase_sh;
    __shared__ int cnt[128];
    __shared__ int scan[128];
    __shared__ int cur[128];
    int b = blockIdx.x, tid = threadIdx.x;
    // --- in-block exclusive scan of min(bcnt[i],BCAP) to get this bucket's global base ---
    int v[4], pre[4];
    int s = 0;
#pragma unroll
    for (int j = 0; j < 4; j++) {
        int idx = tid * 4 + j;
        v[j] = (idx < NBKT) ? min(bcnt[idx], BCAP) : 0;
        pre[j] = s; s += v[j];
    }
    lds[tid] = s;
    __syncthreads();
    for (int off = 1; off < 256; off <<= 1) {
        int t = (tid >= off) ? lds[tid - off] : 0;
        __syncthreads();
        lds[tid] += t;
        __syncthreads();
    }
    if (tid == (b >> 2)) gbase_sh = lds[tid] - s + pre[b & 3];
    if (tid < 128) cnt[tid] = 0;
    __syncthreads();
    int gbase = gbase_sh;
    int n0 = b << 7;
    int m = min(bcnt[b], BCAP);
    const unsigned* bp = bpack + (size_t)b * BCAP;
    for (int j = tid; j < m; j += 256) atomicAdd(&cnt[bp[j] >> 17], 1);
    __syncthreads();
    if (tid < 128) scan[tid] = cnt[tid];
    __syncthreads();
    for (int off = 1; off < 128; off <<= 1) {
        int t = (tid < 128 && tid >= off) ? scan[tid - off] : 0;
        __syncthreads();
        if (tid < 128) scan[tid] += t;
        __syncthreads();
    }
    if (tid < 128) {
        int c = cnt[tid];
        int excl = scan[tid] - c;
        int node = n0 + tid;
        if (node <= N) rp[node] = gbase + excl;
        if (node < N) dinv[node] = rsqrtf((float)(c + 1));  // +1 self loop
        cur[tid] = gbase + excl;
    }
    __syncthreads();
    for (int j = tid; j < m; j += 256) {
        unsigned pk = bp[j];
        int p = atomicAdd(&cur[pk >> 17], 1);
        esrc[p] = (int)(pk & 0x1FFFF);
    }
}

// ---------------- MFMA GEMM (fp32 A): ybf = bf16(dinv * (A @ W)) ----------------
// hi/lo split: A@W = Ahi@Whi + Ahi@Wlo + Alo@Whi. W-hi staged in LDS (reused as
// epilogue scratch after the K loop); W-lo streamed from L2.

__global__ __launch_bounds__(256) void k_gemm_f32(
    const float* __restrict__ A, const unsigned short* __restrict__ wfrag,
    const float* __restrict__ dinv, unsigned short* __restrict__ ybf, int M) {
    __shared__ unsigned short ldsw[4 * 32 * 136];   // K-loop = W-hi(16384); epilogue = scr
    int tid = threadIdx.x, wave = tid >> 6, lane = tid & 63;
    int m = lane & 15, quad = lane >> 4;
    int rowBase = blockIdx.x * 128 + wave * 32;
    int r0 = rowBase + m, r1 = rowBase + 16 + m;
    for (int i = tid; i < 2048; i += 256)
        ((short8*)ldsw)[i] = ((const short8*)wfrag)[i];   // stage W-hi
    __syncthreads();
    f32x4 acc0[8], acc1[8];
#pragma unroll
    for (int i = 0; i < 8; i++) { acc0[i] = (f32x4){0,0,0,0}; acc1[i] = (f32x4){0,0,0,0}; }
    const unsigned short* wlo = wfrag + 16384;

#pragma unroll
    for (int kit = 0; kit < 4; kit++) {
        float a0[8], a1[8];
        if (r0 < M) {
            const float4* ap = (const float4*)(A + (size_t)r0 * 128 + kit * 32 + quad * 8);
            float4 f0 = ap[0], f1 = ap[1];
            a0[0]=f0.x; a0[1]=f0.y; a0[2]=f0.z; a0[3]=f0.w; a0[4]=f1.x; a0[5]=f1.y; a0[6]=f1.z; a0[7]=f1.w;
        } else { for (int j = 0; j < 8; j++) a0[j] = 0.f; }
        if (r1 < M) {
            const float4* ap = (const float4*)(A + (size_t)r1 * 128 + kit * 32 + quad * 8);
            float4 f0 = ap[0], f1 = ap[1];
            a1[0]=f0.x; a1[1]=f0.y; a1[2]=f0.z; a1[3]=f0.w; a1[4]=f1.x; a1[5]=f1.y; a1[6]=f1.z; a1[7]=f1.w;
        } else { for (int j = 0; j < 8; j++) a1[j] = 0.f; }
        short8 ahi0, alo0, ahi1, alo1;
#pragma unroll
        for (int j = 0; j < 8; j++) {
            unsigned short h0 = f2bf(a0[j]);
            ahi0[j] = (short)h0; alo0[j] = (short)f2bf(a0[j] - bf2f(h0));
            unsigned short h1 = f2bf(a1[j]);
            ahi1[j] = (short)h1; alo1[j] = (short)f2bf(a1[j] - bf2f(h1));
        }
        int fb = kit * 4096 + lane * 8;
#pragma unroll
        for (int nt = 0; nt < 8; nt++) {
            int idx = fb + nt * 512;
            short8 bhi = *(const short8*)(ldsw + idx);
            short8 blo = *(const short8*)(wlo + idx);
            acc0[nt] = __builtin_amdgcn_mfma_f32_16x16x32_bf16(ahi0, bhi, acc0[nt], 0, 0, 0);
            acc0[nt] = __builtin_amdgcn_mfma_f32_16x16x32_bf16(alo0, bhi, acc0[nt], 0, 0, 0);
            acc0[nt] = __builtin_amdgcn_mfma_f32_16x16x32_bf16(ahi0, blo, acc0[nt], 0, 0, 0);
            acc1[nt] = __builtin_amdgcn_mfma_f32_16x16x32_bf16(ahi1, bhi, acc1[nt], 0, 0, 0);
            acc1[nt] = __builtin_amdgcn_mfma_f32_16x16x32_bf16(alo1, bhi, acc1[nt], 0, 0, 0);
            acc1[nt] = __builtin_amdgcn_mfma_f32_16x16x32_bf16(ahi1, blo, acc1[nt], 0, 0, 0);
        }
    }
    __syncthreads();   // all waves done reading W-hi before scratch reuse
    // C layout: col = nt*16 + m, row(in tile) = quad*4 + reg
    float dv0 = (r0 < M) ? dinv[r0] : 0.f;
    float dv1 = (r1 < M) ? dinv[r1] : 0.f;
    unsigned short* wsm = ldsw + wave * 32 * 136;
#pragma unroll
    for (int rg = 0; rg < 4; rg++) {
        float s0 = __shfl(dv0, quad * 4 + rg);
        float s1 = __shfl(dv1, quad * 4 + rg);
#pragma unroll
        for (int nt = 0; nt < 8; nt++) {
            wsm[(quad * 4 + rg) * 136 + nt * 16 + m] = f2bf(acc0[nt][rg] * s0);
            wsm[(16 + quad * 4 + rg) * 136 + nt * 16 + m] = f2bf(acc1[nt][rg] * s1);
        }
    }
    __syncthreads();
#pragma unroll
    for (int i = 0; i < 8; i++) {
        int rl = i * 4 + quad;
        int grow = rowBase + rl;
        if (grow < M) {
            short8 v = *(const short8*)(wsm + rl * 136 + m * 8);
            *(short8*)(ybf + (size_t)grow * 128 + m * 8) = v;
        }
    }
}

// ---------------- MFMA GEMM (bf16 A, exact): ybf = bf16(dinv * (A @ W)) ----------------

__global__ __launch_bounds__(256) void k_gemm_bf(
    const unsigned short* __restrict__ A, const unsigned short* __restrict__ wfrag,
    const float* __restrict__ dinv, unsigned short* __restrict__ ybf, int M) {
    __shared__ unsigned short ldsw[4 * 32 * 136];
    int tid = threadIdx.x, wave = tid >> 6, lane = tid & 63;
    int m = lane & 15, quad = lane >> 4;
    int rowBase = blockIdx.x * 128 + wave * 32;
    int r0 = rowBase + m, r1 = rowBase + 16 + m;
    for (int i = tid; i < 2048; i += 256)
        ((short8*)ldsw)[i] = ((const short8*)wfrag)[i];   // stage W-hi
    __syncthreads();
    f32x4 acc0[8], acc1[8];
#pragma unroll
    for (int i = 0; i < 8; i++) { acc0[i] = (f32x4){0,0,0,0}; acc1[i] = (f32x4){0,0,0,0}; }
    const unsigned short* wlo = wfrag + 16384;

#pragma unroll
    for (int kit = 0; kit < 4; kit++) {
        short8 ah0, ah1;
        if (r0 < M) ah0 = *(const short8*)(A + (size_t)r0 * 128 + kit * 32 + quad * 8);
        else { for (int j = 0; j < 8; j++) ah0[j] = 0; }
        if (r1 < M) ah1 = *(const short8*)(A + (size_t)r1 * 128 + kit * 32 + quad * 8);
        else { for (int j = 0; j < 8; j++) ah1[j] = 0; }
        int fb = kit * 4096 + lane * 8;
#pragma unroll
        for (int nt = 0; nt < 8; nt++) {
            int idx = fb + nt * 512;
            short8 bhi = *(const short8*)(ldsw + idx);
            short8 blo = *(const short8*)(wlo + idx);
            acc0[nt] = __builtin_amdgcn_mfma_f32_16x16x32_bf16(ah0, bhi, acc0[nt], 0, 0, 0);
            acc0[nt] = __builtin_amdgcn_mfma_f32_16x16x32_bf16(ah0, blo, acc0[nt], 0, 0, 0);
            acc1[nt] = __builtin_amdgcn_mfma_f32_16x16x32_bf16(ah1, bhi, acc1[nt], 0, 0, 0);
            acc1[nt] = __builtin_amdgcn_mfma_f32_16x16x32_bf16(ah1, blo, acc1[nt], 0, 0, 0);
        }
    }
    __syncthreads();
    float dv0 = (r0 < M) ? dinv[r0] : 0.f;
    float dv1 = (r1 < M) ? dinv[r1] : 0.f;
    unsigned short* wsm = ldsw + wave * 32 * 136;
#pragma unroll
    for (int rg = 0; rg < 4; rg++) {
        float s0 = __shfl(dv0, quad * 4 + rg);
        float s1 = __shfl(dv1, quad * 4 + rg);
#pragma unroll
        for (int nt = 0; nt < 8; nt++) {
            wsm[(quad * 4 + rg) * 136 + nt * 16 + m] = f2bf(acc0[nt][rg] * s0);
            wsm[(16 + quad * 4 + rg) * 136 + nt * 16 + m] = f2bf(acc1[nt][rg] * s1);
        }
    }
    __syncthreads();
#pragma unroll
    for (int i = 0; i < 8; i++) {
        int rl = i * 4 + quad;
        int grow = rowBase + rl;
        if (grow < M) {
            short8 v = *(const short8*)(wsm + rl * 136 + m * 8);
            *(short8*)(ybf + (size_t)grow * 128 + m * 8) = v;
        }
    }
}

// ---------------- CSR aggregation (bf16 gather, wave-per-node, shfl-broadcast esrc) ----------------
// One coalesced esrc load per 64 edges + __shfl distribute -> ~1 vmem instr/edge.
// Fabric-service bound: FETCH ~= working_set(25.6MB) x 8 XCDs @ ~3 TB/s (R7/R9 measured).

__global__ __launch_bounds__(256) void k_agg(
    const unsigned short* __restrict__ y, const float* __restrict__ dinv,
    const int* __restrict__ rp, const int* __restrict__ esrc,
    const float* __restrict__ bias, unsigned* __restrict__ out, int relu, int N) {
    int wave = threadIdx.x >> 6;
    int lane = threadIdx.x & 63;
    int node = blockIdx.x * 4 + wave;
    if (node >= N) return;
    const unsigned* y2 = (const unsigned*)y;   // 2 bf16 per u32, row stride 64
    unsigned vs = y2[(size_t)node * 64 + lane];       // self loop
    float a0 = bf2f(vs & 0xFFFF), a1 = bf2f(vs >> 16);
    int beg = rp[node], end = rp[node + 1];
    int j = beg;
    while (j < end) {
        int idxv = (j + lane < end) ? esrc[j + lane] : 0;
        int cnt = end - j; if (cnt > 64) cnt = 64;
        int i = 0;
        for (; i + 4 <= cnt; i += 4) {
            int s0 = __shfl(idxv, i + 0);
            int s1 = __shfl(idxv, i + 1);
            int s2 = __shfl(idxv, i + 2);
            int s3 = __shfl(idxv, i + 3);
            unsigned v0 = y2[(size_t)s0 * 64 + lane];
            unsigned v1 = y2[(size_t)s1 * 64 + lane];
            unsigned v2 = y2[(size_t)s2 * 64 + lane];
            unsigned v3 = y2[(size_t)s3 * 64 + lane];
            a0 += bf2f(v0 & 0xFFFF); a1 += bf2f(v0 >> 16);
            a0 += bf2f(v1 & 0xFFFF); a1 += bf2f(v1 >> 16);
            a0 += bf2f(v2 & 0xFFFF); a1 += bf2f(v2 >> 16);
            a0 += bf2f(v3 & 0xFFFF); a1 += bf2f(v3 >> 16);
        }
        for (; i < cnt; i++) {
            int s = __shfl(idxv, i);
            unsigned v = y2[(size_t)s * 64 + lane];
            a0 += bf2f(v & 0xFFFF); a1 += bf2f(v >> 16);
        }
        j += cnt;
    }
    float s = dinv[node];
    float2 bv = ((const float2*)bias)[lane];
    float o0 = s * a0 + bv.x;
    float o1 = s * a1 + bv.y;
    if (relu) { o0 = fmaxf(o0, 0.f); o1 = fmaxf(o1, 0.f); }
    out[(size_t)node * 64 + lane] = (unsigned)f2bf(o0) | ((unsigned)f2bf(o1) << 16);
}

// ---------------- fused mean-pool + classifier head ----------------

__global__ __launch_bounds__(256) void k_poolhead(
    const unsigned* __restrict__ h2, const int* __restrict__ batch,
    const float* __restrict__ Wc, const float* __restrict__ bc,
    float* __restrict__ out, int n) {
    __shared__ float2 red[4][64];
    __shared__ float grow[DIM];
    int gid = blockIdx.x;
    int tid = threadIdx.x, wave = tid >> 6, lane = tid & 63;
    int lo = 0, hi = n;
    while (lo < hi) { int mid = (lo + hi) >> 1; if (batch[mid] < gid) lo = mid + 1; else hi = mid; }
    int start = lo;
    hi = n;
    while (lo < hi) { int mid = (lo + hi) >> 1; if (batch[mid] < gid + 1) lo = mid + 1; else hi = mid; }
    int end = lo;
    float a0 = 0.f, a1 = 0.f;
    for (int r = start + wave; r < end; r += 4) {
        unsigned v = h2[(size_t)r * 64 + lane];
        a0 += bf2f(v & 0xFFFF); a1 += bf2f(v >> 16);
    }
    red[wave][lane] = make_float2(a0, a1);
    __syncthreads();
    if (tid < 64) {
        float2 s = red[0][tid];
        s.x += red[1][tid].x; s.y += red[1][tid].y;
        s.x += red[2][tid].x; s.y += red[2][tid].y;
        s.x += red[3][tid].x; s.y += red[3][tid].y;
        int cnt = end - start;
        float inv = 1.f / (float)(cnt > 0 ? cnt : 1);
        grow[tid * 2] = s.x * inv;
        grow[tid * 2 + 1] = s.y * inv;
    }
    __syncthreads();
    if (tid < NCLS) {
        float acc = bc[tid];
#pragma unroll 16
        for (int k = 0; k < DIM; k++) acc += grow[k] * Wc[k * NCLS + tid];
        out[gid * NCLS + tid] = acc;
    }
}

extern "C" void kernel_launch(void* const* d_in, const int* in_sizes, int n_in,
                              void* d_out, int out_size, void* d_ws, size_t ws_size,
                              hipStream_t stream) {
    const float* x    = (const float*)d_in[0];
    const int*   ei   = (const int*)d_in[1];
    const int*   batch= (const int*)d_in[2];
    const float* W1   = (const float*)d_in[3];
    const float* b1   = (const float*)d_in[4];
    const float* W2   = (const float*)d_in[5];
    const float* b2   = (const float*)d_in[6];
    const float* Wc   = (const float*)d_in[7];
    const float* bc   = (const float*)d_in[8];
    float* out = (float*)d_out;
    const int N = N_NODES, E = N_EDGES;
    const int* src = ei;
    const int* dst = ei + E;

    char* ws = (char*)d_ws;
    size_t off = 0;
    auto carve = [&](size_t bytes) -> void* {
        void* p = ws + off;
        off = (off + bytes + 255) & ~(size_t)255;
        return p;
    };
    int*      rp    = (int*)     carve((size_t)(N + 1) * 4);
    float*    dinv  = (float*)   carve((size_t)N * 4);
    int*      bcnt  = (int*)     carve(NBKT * 4);
    unsigned* bpack = (unsigned*)carve((size_t)NBKT * BCAP * 4);
    int*      esrc  = (int*)     carve((size_t)E * 4);
    unsigned short* wf1 = (unsigned short*)carve(2 * 16384 * 2);
    unsigned short* wf2 = (unsigned short*)carve(2 * 16384 * 2);
    unsigned short* bufY = (unsigned short*)carve((size_t)N * DIM * 2);
    unsigned short* bufH = (unsigned short*)carve((size_t)N * DIM * 2);
    (void)ws_size; (void)n_in; (void)in_sizes; (void)out_size;

    hipLaunchKernelGGL(k_wprep,  dim3(128 + (NBKT + 255) / 256), dim3(256), 0, stream, W1, W2, wf1, wf2, bcnt);
    hipLaunchKernelGGL(k_bucket, dim3((E + 4095) / 4096), dim3(256), 0, stream, src, dst, bcnt, bpack, E);
    hipLaunchKernelGGL(k_bsort,  dim3(NBKT), dim3(256), 0, stream, bpack, bcnt, rp, dinv, esrc, N);

    int gemmGrid = (N + 127) / 128;  // 782
    // conv1: Y1 = bf16(dinv*(x@W1)); H1 = bf16(relu(dinv*agg(Y1)+b1))
    hipLaunchKernelGGL(k_gemm_f32, dim3(gemmGrid), dim3(256), 0, stream, x, wf1, dinv, bufY, N);
    hipLaunchKernelGGL(k_agg, dim3((N + 3) / 4), dim3(256), 0, stream, bufY, dinv, rp, esrc, b1, (unsigned*)bufH, 1, N);
    // conv2
    hipLaunchKernelGGL(k_gemm_bf, dim3(gemmGrid), dim3(256), 0, stream, bufH, wf2, dinv, bufY, N);
    hipLaunchKernelGGL(k_agg, dim3((N + 3) / 4), dim3(256), 0, stream, bufY, dinv, rp, esrc, b2, (unsigned*)bufH, 0, N);
    // fused pool + head
    hipLaunchKernelGGL(k_poolhead, dim3(N_GRAPHS), dim3(256), 0, stream, (const unsigned*)bufH, batch, Wc, bc, out, N);
}